// Round 6
// baseline (220.249 us; speedup 1.0000x reference)
//
#include <hip/hip_runtime.h>
#include <hip/hip_bf16.h>
#include <cmath>

// ---------- problem constants ----------
constexpr int CB = 8, CS = 2048, CDV = 768, CDA = 512, CK = 512;
constexpr int CM = CB * CS;             // 16384 rows (b,s)

// ---------- types ----------
typedef __attribute__((ext_vector_type(4))) float f4v;   // MFMA acc / fp32 loads
typedef __attribute__((ext_vector_type(4))) int   i4v;   // 16B load
typedef __attribute__((ext_vector_type(8))) int   v8i;   // fp8 MFMA A/B frag (32 bytes)

template<bool HI>
__device__ __forceinline__ unsigned int pk2(float a, float b, unsigned int old) {
    return (unsigned int)__builtin_amdgcn_cvt_pk_fp8_f32(a, b, (int)old, HI);
}
__device__ __forceinline__ unsigned char f2f8(float x) {
    return (unsigned char)(__builtin_amdgcn_cvt_pk_fp8_f32(x, 0.f, 0, false) & 0xFF);
}

// ---------- prep: fp8 convert + window-3 temporal smooth (both modalities) ----------
template<int D>
__device__ __forceinline__ void smooth8(const float* __restrict__ f,
                                        unsigned char* __restrict__ g,
                                        unsigned char* __restrict__ sm,
                                        int idx)
{
    int dch = idx % (D / 8);
    int bs  = idx / (D / 8);
    int t   = bs % CS;
    const f4v* fp = (const f4v*)f;
    int b4 = bs * (D / 4) + dch * 2;
    f4v c0 = fp[b4], c1 = fp[b4 + 1];
    f4v a0 = c0, a1 = c1;
    float cnt = 1.f;
    if (t > 0)      { a0 += fp[b4 - D / 4]; a1 += fp[b4 - D / 4 + 1]; cnt += 1.f; }
    if (t < CS - 1) { a0 += fp[b4 + D / 4]; a1 += fp[b4 + D / 4 + 1]; cnt += 1.f; }
    float inv = 1.f / cnt;

    unsigned int glo = pk2<false>(c0[0], c0[1], 0u); glo = pk2<true>(c0[2], c0[3], glo);
    unsigned int ghi = pk2<false>(c1[0], c1[1], 0u); ghi = pk2<true>(c1[2], c1[3], ghi);
    unsigned int slo = pk2<false>(a0[0] * inv, a0[1] * inv, 0u); slo = pk2<true>(a0[2] * inv, a0[3] * inv, slo);
    unsigned int shi = pk2<false>(a1[0] * inv, a1[1] * inv, 0u); shi = pk2<true>(a1[2] * inv, a1[3] * inv, shi);
    ((uint2*)g)[idx]  = make_uint2(glo, ghi);
    ((uint2*)sm)[idx] = make_uint2(slo, shi);
}

__global__ void prep_smooth_all(const float* __restrict__ fv, const float* __restrict__ fa,
                                unsigned char* __restrict__ Gv, unsigned char* __restrict__ Sv,
                                unsigned char* __restrict__ Ga, unsigned char* __restrict__ Sa)
{
    int idx = blockIdx.x * 256 + threadIdx.x;
    constexpr int NV = CM * (CDV / 8);
    constexpr int NA = CM * (CDA / 8);
    if (idx < NV)            smooth8<CDV>(fv, Gv, Sv, idx);
    else if (idx < NV + NA)  smooth8<CDA>(fa, Ga, Sa, idx - NV);
}

// ---------- small prep: proto fp8 convert + proj transpose->fp8 (one launch) ----------
__device__ __forceinline__ void conv8(const float* __restrict__ in,
                                      unsigned char* __restrict__ out, int i)
{
    const f4v* fp = (const f4v*)in;
    f4v c0 = fp[2 * i], c1 = fp[2 * i + 1];
    unsigned int lo = pk2<false>(c0[0], c0[1], 0u); lo = pk2<true>(c0[2], c0[3], lo);
    unsigned int hi = pk2<false>(c1[0], c1[1], 0u); hi = pk2<true>(c1[2], c1[3], hi);
    ((uint2*)out)[i] = make_uint2(lo, hi);
}

__global__ void prep_small(const float* __restrict__ pv, const float* __restrict__ pa,
                           const float* __restrict__ wv, const float* __restrict__ wa,
                           unsigned char* __restrict__ Pv, unsigned char* __restrict__ Pa,
                           unsigned char* __restrict__ WvT, unsigned char* __restrict__ WaT)
{
    int idx = blockIdx.x * 256 + threadIdx.x;
    constexpr int N1 = CK * CDV / 8;
    constexpr int N2 = CK * CDA / 8;
    constexpr int N3 = CDV * CDA;
    if (idx < N1) { conv8(pv, Pv, idx); return; }
    idx -= N1;
    if (idx < N2) { conv8(pa, Pa, idx); return; }
    idx -= N2;
    if (idx < N3) {   // wv (768x512) -> WvT (512x768)
        int r = idx % CDV, c = idx / CDV;
        WvT[(size_t)c * CDV + r] = f2f8(wv[(size_t)r * CDA + c]);
        return;
    }
    idx -= N3;
    if (idx < N3) {   // wa (512x768) -> WaT (768x512)
        int r = idx % CDA, c = idx / CDA;
        WaT[(size_t)c * CDA + r] = f2f8(wa[(size_t)r * CDV + c]);
    }
}

// ---------- shared helpers ----------
__device__ __forceinline__ v8i ld_frag(const unsigned char* base, int row, int hi)
{
    int c0 = (2 * hi) ^ (row & 7);          // global chunk 2*hi   -> k bytes [32hi,32hi+16)
    int c1 = c0 ^ 1;                        // global chunk 2*hi+1 -> k bytes [32hi+16,32hi+32)
    i4v lo = *(const i4v*)(base + row * 128 + c0 * 16);
    i4v h  = *(const i4v*)(base + row * 128 + c1 * 16);
    v8i r;
    r[0] = lo[0]; r[1] = lo[1]; r[2] = lo[2]; r[3] = lo[3];
    r[4] = h[0];  r[5] = h[1];  r[6] = h[2];  r[7] = h[3];
    return r;
}

#define MFMA_FP8(a, b, c) __builtin_amdgcn_mfma_scale_f32_16x16x128_f8f6f4( \
        (a), (b), (c), 0, 0, 0, 0x7F7F7F7F, 0, 0x7F7F7F7F)

// ---------- legacy LDS-staged engine (used by small combine GEMM only) ----------
__device__ __forceinline__ void gemm_phase_fp8(
    const unsigned char* __restrict__ A,
    const unsigned char* __restrict__ BT,
    int D, int bm, int bn, int tid,
    unsigned char* As, unsigned char* Bs,
    f4v (&acc)[4][4])
{
    const int lane = tid & 63;
    const int w    = tid >> 6;
    const int wr   = (w >> 1) * 64;
    const int wc   = (w & 1) * 64;
    const int lr   = lane & 15;
    const int hi   = lane >> 4;

    const unsigned char* gA[4];
    const unsigned char* gB[4];
    int wb[4];
#pragma unroll
    for (int it = 0; it < 4; ++it) {
        int idx = it * 256 + tid;
        int row = idx >> 3;
        int sch = (idx & 7) ^ (row & 7);
        wb[it]  = (idx & ~63) * 16;
        gA[it]  = A  + (size_t)(bm + row) * D + sch * 16;
        gB[it]  = BT + (size_t)(bn + row) * D + sch * 16;
    }

    auto stage = [&](int buf, int d0) {
#pragma unroll
        for (int it = 0; it < 4; ++it) {
            __builtin_amdgcn_global_load_lds(
                (const __attribute__((address_space(1))) unsigned int*)(gA[it] + d0),
                (__attribute__((address_space(3))) unsigned int*)(As + buf * 16384 + wb[it]),
                16, 0, 0);
            __builtin_amdgcn_global_load_lds(
                (const __attribute__((address_space(1))) unsigned int*)(gB[it] + d0),
                (__attribute__((address_space(3))) unsigned int*)(Bs + buf * 16384 + wb[it]),
                16, 0, 0);
        }
    };

    __syncthreads();
    stage(0, 0);
    asm volatile("s_waitcnt vmcnt(0)" ::: "memory");
    __syncthreads();

    const int nt = D >> 7;
    int cur = 0;
    for (int t = 0; t < nt; ++t) {
        if (t + 1 < nt) stage(cur ^ 1, (t + 1) << 7);
        const unsigned char* Ab = As + cur * 16384;
        const unsigned char* Bb = Bs + cur * 16384;
        v8i af[4], bfr[4];
#pragma unroll
        for (int f = 0; f < 4; ++f) {
            af[f]  = ld_frag(Ab, wr + f * 16 + lr, hi);
            bfr[f] = ld_frag(Bb, wc + f * 16 + lr, hi);
        }
#pragma unroll
        for (int i = 0; i < 4; ++i)
#pragma unroll
            for (int j = 0; j < 4; ++j)
                acc[i][j] = MFMA_FP8(af[i], bfr[j], acc[i][j]);
        if (t + 1 < nt) {
            asm volatile("s_waitcnt vmcnt(0)" ::: "memory");
            __syncthreads();
            cur ^= 1;
        }
    }
}

// ---------- combine GEMMs (both modalities, one launch), fp8 out ----------
__global__ void __launch_bounds__(256)
gemm_combine2(const unsigned char* __restrict__ Pv, const unsigned char* __restrict__ WvT,
              unsigned char* __restrict__ Cv,
              const unsigned char* __restrict__ Pa, const unsigned char* __restrict__ WaT,
              unsigned char* __restrict__ Ca)
{
    __shared__ __align__(16) unsigned char As[2 * 16384];
    __shared__ __align__(16) unsigned char Bs[2 * 16384];
    int id = blockIdx.x;
    const unsigned char *A, *BT; unsigned char* C; int D, N, bm, bn;
    if (id < 16) { A = Pv; BT = WvT; C = Cv; D = CDV; N = CDA; bm = (id & 3) * 128; bn = (id >> 2) * 128; }
    else { id -= 16; A = Pa; BT = WaT; C = Ca; D = CDA; N = CDV; bm = (id & 3) * 128; bn = (id >> 2) * 128; }

    f4v acc[4][4] = {};
    int tid = threadIdx.x;
    gemm_phase_fp8(A, BT, D, bm, bn, tid, As, Bs, acc);

    const int lane = tid & 63;
    const int w    = tid >> 6;
    const int wr   = (w >> 1) * 64, wc = (w & 1) * 64;
    const int row0 = (lane >> 4) * 4, col = lane & 15;
#pragma unroll
    for (int i = 0; i < 4; ++i)
#pragma unroll
        for (int j = 0; j < 4; ++j)
#pragma unroll
            for (int e = 0; e < 4; ++e) {
                int m = bm + wr + i * 16 + row0 + e;
                int n = bn + wc + j * 16 + col;
                C[(size_t)m * N + n] = f2f8(acc[i][j][e]);
            }
}

// ---------- fused dual-GEMM + softplus-energy reduce ----------
// A (features) streamed global->registers (per-wave-exclusive rows; L2/L3 serves
// bn-duplicates). Only B (protos/comb, L2-resident) staged via global_load_lds
// into a 2-buffer 32 KB LDS ring. Counted vmcnt(8) publish (B's 4 loads) + raw
// s_barrier: the 8 in-flight A-loads are never drained at the barrier (T4).
// Merged 10-step K-loop: steps 0-5 = intra (D=768), 6-9 = cross (D=512).
__global__ void __launch_bounds__(256, 2)
fused_energy(const unsigned char* __restrict__ Gv, const unsigned char* __restrict__ Pv,
             const unsigned char* __restrict__ Ga, const unsigned char* __restrict__ Pa,
             const unsigned char* __restrict__ Sa, const unsigned char* __restrict__ Cv,
             const unsigned char* __restrict__ Sv, const unsigned char* __restrict__ Ca,
             float* __restrict__ out)
{
    __shared__ __align__(16) unsigned char Bs[2][16384];
    const unsigned char *A1, *B1, *A2, *B2; int D1, D2, NT1;
    if (blockIdx.z == 0) { A1 = Gv; B1 = Pv; D1 = CDV; A2 = Sa; B2 = Cv; D2 = CDA; NT1 = 6; }
    else                 { A1 = Ga; B1 = Pa; D1 = CDA; A2 = Sv; B2 = Ca; D2 = CDV; NT1 = 4; }
    constexpr int NT = 10;                   // (768+512)/128

    const int tid  = threadIdx.x;
    const int lane = tid & 63;
    const int w    = tid >> 6;
    const int wr   = (w >> 1) * 64;
    const int wc   = (w & 1) * 64;
    const int lr   = lane & 15;
    const int hi   = lane >> 4;
    const int bm   = blockIdx.x * 128, bn = blockIdx.y * 128;

    // B staging bases (pre-swizzled source chunk), wave-uniform LDS dest
    const unsigned char* gB1[4];
    const unsigned char* gB2[4];
    int wbase[4];
#pragma unroll
    for (int it = 0; it < 4; ++it) {
        int idx   = it * 256 + tid;
        int row   = idx >> 3;
        int sch   = (idx & 7) ^ (row & 7);
        wbase[it] = (it * 256 + w * 64) * 16;
        gB1[it]   = B1 + (size_t)(bn + row) * D1 + sch * 16;
        gB2[it]   = B2 + (size_t)(bn + row) * D2 + sch * 16;
    }
    // A fragment base pointers (per-lane direct global)
    const unsigned char* pA1[4];
    const unsigned char* pA2[4];
#pragma unroll
    for (int f = 0; f < 4; ++f) {
        size_t row = (size_t)(bm + wr + f * 16 + lr);
        pA1[f] = A1 + row * D1 + hi * 32;
        pA2[f] = A2 + row * D2 + hi * 32;
    }

    auto stageB = [&](int buf, int t) {
#pragma unroll
        for (int it = 0; it < 4; ++it) {
            const unsigned char* src = (t < NT1) ? gB1[it] + t * 128
                                                 : gB2[it] + (t - NT1) * 128;
            __builtin_amdgcn_global_load_lds(
                (const __attribute__((address_space(1))) unsigned int*)src,
                (__attribute__((address_space(3))) unsigned int*)(&Bs[buf][0] + wbase[it]),
                16, 0, 0);
        }
    };

    v8i areg[2][4];
    auto loadA = [&](int bank, int t) {
#pragma unroll
        for (int f = 0; f < 4; ++f) {
            const unsigned char* p = (t < NT1) ? pA1[f] + t * 128
                                               : pA2[f] + (t - NT1) * 128;
            i4v lo = *(const i4v*)p;
            i4v h  = *(const i4v*)(p + 16);
            v8i r;
            r[0] = lo[0]; r[1] = lo[1]; r[2] = lo[2]; r[3] = lo[3];
            r[4] = h[0];  r[5] = h[1];  r[6] = h[2];  r[7] = h[3];
            areg[bank][f] = r;
        }
    };

    f4v acc1[4][4] = {};
    f4v acc2[4][4] = {};

    // prologue: B(0) then A(0); counted wait covers B(0) only
    stageB(0, 0);
    asm volatile("" ::: "memory");
    loadA(0, 0);
    asm volatile("s_waitcnt vmcnt(8)" ::: "memory");
    __builtin_amdgcn_s_barrier();
    asm volatile("" ::: "memory");

#pragma unroll
    for (int t = 0; t < NT; ++t) {
        const int buf = t & 1;
        // 1. B fragments for this step
        v8i bfr[4];
#pragma unroll
        for (int j = 0; j < 4; ++j)
            bfr[j] = ld_frag(&Bs[buf][0], wc + j * 16 + lr, hi);
        // 2. issue next B stage, then next A loads (order pinned by fences)
        if (t + 1 < NT) stageB(buf ^ 1, t + 1);
        asm volatile("" ::: "memory");
        if (t + 1 < NT) loadA((t + 1) & 1, t + 1);
        // 3. MFMA cluster on current A bank
        __builtin_amdgcn_s_setprio(1);
        if (t < NT1) {
#pragma unroll
            for (int i = 0; i < 4; ++i)
#pragma unroll
                for (int j = 0; j < 4; ++j)
                    acc1[i][j] = MFMA_FP8(areg[t & 1][i], bfr[j], acc1[i][j]);
        } else {
#pragma unroll
            for (int i = 0; i < 4; ++i)
#pragma unroll
                for (int j = 0; j < 4; ++j)
                    acc2[i][j] = MFMA_FP8(areg[t & 1][i], bfr[j], acc2[i][j]);
        }
        __builtin_amdgcn_s_setprio(0);
        // 4. publish next B tile: wait its 4 loads (A's 8 stay in flight), barrier
        asm volatile("s_waitcnt vmcnt(8)" ::: "memory");
        __builtin_amdgcn_s_barrier();
        asm volatile("" ::: "memory");
    }

    float local = 0.f;
#pragma unroll
    for (int i = 0; i < 4; ++i)
#pragma unroll
        for (int j = 0; j < 4; ++j)
#pragma unroll
            for (int e = 0; e < 4; ++e) {
                float iv = acc1[i][j][e];
                float cv = acc2[i][j][e];
                float sal = 0.3f * cv * cv + 0.7f * iv * iv;
                float t   = sal * iv;
                local += fmaxf(t, 0.f) + __logf(1.f + __expf(-fabsf(t)));
            }
#pragma unroll
    for (int o = 32; o > 0; o >>= 1) local += __shfl_down(local, o);
    __shared__ float wred[4];
    if (lane == 0) wred[w] = local;
    __syncthreads();
    if (tid == 0) atomicAdd(out, -(wred[0] + wred[1] + wred[2] + wred[3]));
}

// ---------- launch ----------
extern "C" void kernel_launch(void* const* d_in, const int* in_sizes, int n_in,
                              void* d_out, int out_size, void* d_ws, size_t ws_size,
                              hipStream_t stream)
{
    const float* fv = (const float*)d_in[0];   // (8,2048,768)
    const float* fa = (const float*)d_in[1];   // (8,2048,512)
    const float* pv = (const float*)d_in[2];   // (512,768)
    const float* pa = (const float*)d_in[3];   // (512,512)
    const float* wv = (const float*)d_in[4];   // (768,512) proj_audio_to_vision
    const float* wa = (const float*)d_in[5];   // (512,768) proj_vision_to_audio
    float* out = (float*)d_out;

    size_t off = 0;
    auto carve = [&](size_t bytes) {
        unsigned char* p = (unsigned char*)d_ws + off;
        off += ((bytes + 255) & ~(size_t)255);
        return p;
    };
    unsigned char* Gv  = carve((size_t)CM * CDV);
    unsigned char* Sv  = carve((size_t)CM * CDV);
    unsigned char* Ga  = carve((size_t)CM * CDA);
    unsigned char* Sa  = carve((size_t)CM * CDA);
    unsigned char* Pv  = carve((size_t)CK * CDV);
    unsigned char* Pa  = carve((size_t)CK * CDA);
    unsigned char* WvT = carve((size_t)CDA * CDV);
    unsigned char* WaT = carve((size_t)CDV * CDA);
    unsigned char* Cv  = carve((size_t)CK * CDA);
    unsigned char* Ca  = carve((size_t)CK * CDV);

    (void)hipMemsetAsync(d_out, 0, sizeof(float), stream);

    constexpr int NS = CM * (CDV / 8) + CM * (CDA / 8);
    prep_smooth_all<<<(NS + 255) / 256, 256, 0, stream>>>(fv, fa, Gv, Sv, Ga, Sa);

    constexpr int NP = CK * CDV / 8 + CK * CDA / 8 + 2 * CDV * CDA;
    prep_small<<<(NP + 255) / 256, 256, 0, stream>>>(pv, pa, wv, wa, Pv, Pa, WvT, WaT);

    gemm_combine2<<<16 + 24, 256, 0, stream>>>(Pv, WvT, Cv, Pa, WaT, Ca);

    fused_energy<<<dim3(CM / 128, CK / 128, 2), 256, 0, stream>>>(
        Gv, Pv, Ga, Pa, Sa, Cv, Sv, Ca, out);
}

// Round 7
// 208.526 us; speedup vs baseline: 1.0562x; 1.0562x over previous
//
#include <hip/hip_runtime.h>
#include <hip/hip_bf16.h>
#include <cmath>

// ---------- problem constants ----------
constexpr int CB = 8, CS = 2048, CDV = 768, CDA = 512, CK = 512;
constexpr int CM = CB * CS;             // 16384 rows (b,s)

// ---------- types ----------
typedef __attribute__((ext_vector_type(4))) float f4v;   // MFMA acc / fp32 loads
typedef __attribute__((ext_vector_type(4))) int   i4v;   // 16B load
typedef __attribute__((ext_vector_type(8))) int   v8i;   // fp8 MFMA A/B frag (32 bytes)

template<bool HI>
__device__ __forceinline__ unsigned int pk2(float a, float b, unsigned int old) {
    return (unsigned int)__builtin_amdgcn_cvt_pk_fp8_f32(a, b, (int)old, HI);
}
__device__ __forceinline__ unsigned char f2f8(float x) {
    return (unsigned char)(__builtin_amdgcn_cvt_pk_fp8_f32(x, 0.f, 0, false) & 0xFF);
}

// ---------- prep: fp8 convert + window-3 temporal smooth (both modalities) ----------
template<int D>
__device__ __forceinline__ void smooth8(const float* __restrict__ f,
                                        unsigned char* __restrict__ g,
                                        unsigned char* __restrict__ sm,
                                        int idx)
{
    int dch = idx % (D / 8);
    int bs  = idx / (D / 8);
    int t   = bs % CS;
    const f4v* fp = (const f4v*)f;
    int b4 = bs * (D / 4) + dch * 2;
    f4v c0 = fp[b4], c1 = fp[b4 + 1];
    f4v a0 = c0, a1 = c1;
    float cnt = 1.f;
    if (t > 0)      { a0 += fp[b4 - D / 4]; a1 += fp[b4 - D / 4 + 1]; cnt += 1.f; }
    if (t < CS - 1) { a0 += fp[b4 + D / 4]; a1 += fp[b4 + D / 4 + 1]; cnt += 1.f; }
    float inv = 1.f / cnt;

    unsigned int glo = pk2<false>(c0[0], c0[1], 0u); glo = pk2<true>(c0[2], c0[3], glo);
    unsigned int ghi = pk2<false>(c1[0], c1[1], 0u); ghi = pk2<true>(c1[2], c1[3], ghi);
    unsigned int slo = pk2<false>(a0[0] * inv, a0[1] * inv, 0u); slo = pk2<true>(a0[2] * inv, a0[3] * inv, slo);
    unsigned int shi = pk2<false>(a1[0] * inv, a1[1] * inv, 0u); shi = pk2<true>(a1[2] * inv, a1[3] * inv, shi);
    ((uint2*)g)[idx]  = make_uint2(glo, ghi);
    ((uint2*)sm)[idx] = make_uint2(slo, shi);
}

__global__ void prep_smooth_all(const float* __restrict__ fv, const float* __restrict__ fa,
                                unsigned char* __restrict__ Gv, unsigned char* __restrict__ Sv,
                                unsigned char* __restrict__ Ga, unsigned char* __restrict__ Sa)
{
    int idx = blockIdx.x * 256 + threadIdx.x;
    constexpr int NV = CM * (CDV / 8);
    constexpr int NA = CM * (CDA / 8);
    if (idx < NV)            smooth8<CDV>(fv, Gv, Sv, idx);
    else if (idx < NV + NA)  smooth8<CDA>(fa, Ga, Sa, idx - NV);
}

// ---------- small prep: proto fp8 convert + proj transpose->fp8 (one launch) ----------
__device__ __forceinline__ void conv8(const float* __restrict__ in,
                                      unsigned char* __restrict__ out, int i)
{
    const f4v* fp = (const f4v*)in;
    f4v c0 = fp[2 * i], c1 = fp[2 * i + 1];
    unsigned int lo = pk2<false>(c0[0], c0[1], 0u); lo = pk2<true>(c0[2], c0[3], lo);
    unsigned int hi = pk2<false>(c1[0], c1[1], 0u); hi = pk2<true>(c1[2], c1[3], hi);
    ((uint2*)out)[i] = make_uint2(lo, hi);
}

__global__ void prep_small(const float* __restrict__ pv, const float* __restrict__ pa,
                           const float* __restrict__ wv, const float* __restrict__ wa,
                           unsigned char* __restrict__ Pv, unsigned char* __restrict__ Pa,
                           unsigned char* __restrict__ WvT, unsigned char* __restrict__ WaT)
{
    int idx = blockIdx.x * 256 + threadIdx.x;
    constexpr int N1 = CK * CDV / 8;
    constexpr int N2 = CK * CDA / 8;
    constexpr int N3 = CDV * CDA;
    if (idx < N1) { conv8(pv, Pv, idx); return; }
    idx -= N1;
    if (idx < N2) { conv8(pa, Pa, idx); return; }
    idx -= N2;
    if (idx < N3) {   // wv (768x512) -> WvT (512x768)
        int r = idx % CDV, c = idx / CDV;
        WvT[(size_t)c * CDV + r] = f2f8(wv[(size_t)r * CDA + c]);
        return;
    }
    idx -= N3;
    if (idx < N3) {   // wa (512x768) -> WaT (768x512)
        int r = idx % CDA, c = idx / CDA;
        WaT[(size_t)c * CDA + r] = f2f8(wa[(size_t)r * CDV + c]);
    }
}

// ---------- shared helpers ----------
__device__ __forceinline__ v8i ld_frag(const unsigned char* base, int row, int hi)
{
    int c0 = (2 * hi) ^ (row & 7);          // global chunk 2*hi
    int c1 = c0 ^ 1;                        // global chunk 2*hi+1
    i4v lo = *(const i4v*)(base + row * 128 + c0 * 16);
    i4v h  = *(const i4v*)(base + row * 128 + c1 * 16);
    v8i r;
    r[0] = lo[0]; r[1] = lo[1]; r[2] = lo[2]; r[3] = lo[3];
    r[4] = h[0];  r[5] = h[1];  r[6] = h[2];  r[7] = h[3];
    return r;
}

#define MFMA_FP8(a, b, c) __builtin_amdgcn_mfma_scale_f32_16x16x128_f8f6f4( \
        (a), (b), (c), 0, 0, 0, 0x7F7F7F7F, 0, 0x7F7F7F7F)

// ---------- LDS-staged engine (used by small combine GEMM only; proven R5) ----------
__device__ __forceinline__ void gemm_phase_fp8(
    const unsigned char* __restrict__ A,
    const unsigned char* __restrict__ BT,
    int D, int bm, int bn, int tid,
    unsigned char* As, unsigned char* Bs,
    f4v (&acc)[4][4])
{
    const int lane = tid & 63;
    const int w    = tid >> 6;
    const int wr   = (w >> 1) * 64;
    const int wc   = (w & 1) * 64;
    const int lr   = lane & 15;
    const int hi   = lane >> 4;

    const unsigned char* gA[4];
    const unsigned char* gB[4];
    int wb[4];
#pragma unroll
    for (int it = 0; it < 4; ++it) {
        int idx = it * 256 + tid;
        int row = idx >> 3;
        int sch = (idx & 7) ^ (row & 7);
        wb[it]  = (idx & ~63) * 16;
        gA[it]  = A  + (size_t)(bm + row) * D + sch * 16;
        gB[it]  = BT + (size_t)(bn + row) * D + sch * 16;
    }

    auto stage = [&](int buf, int d0) {
#pragma unroll
        for (int it = 0; it < 4; ++it) {
            __builtin_amdgcn_global_load_lds(
                (const __attribute__((address_space(1))) unsigned int*)(gA[it] + d0),
                (__attribute__((address_space(3))) unsigned int*)(As + buf * 16384 + wb[it]),
                16, 0, 0);
            __builtin_amdgcn_global_load_lds(
                (const __attribute__((address_space(1))) unsigned int*)(gB[it] + d0),
                (__attribute__((address_space(3))) unsigned int*)(Bs + buf * 16384 + wb[it]),
                16, 0, 0);
        }
    };

    __syncthreads();
    stage(0, 0);
    asm volatile("s_waitcnt vmcnt(0)" ::: "memory");
    __syncthreads();

    const int nt = D >> 7;
    int cur = 0;
    for (int t = 0; t < nt; ++t) {
        if (t + 1 < nt) stage(cur ^ 1, (t + 1) << 7);
        const unsigned char* Ab = As + cur * 16384;
        const unsigned char* Bb = Bs + cur * 16384;
        v8i af[4], bfr[4];
#pragma unroll
        for (int f = 0; f < 4; ++f) {
            af[f]  = ld_frag(Ab, wr + f * 16 + lr, hi);
            bfr[f] = ld_frag(Bb, wc + f * 16 + lr, hi);
        }
#pragma unroll
        for (int i = 0; i < 4; ++i)
#pragma unroll
            for (int j = 0; j < 4; ++j)
                acc[i][j] = MFMA_FP8(af[i], bfr[j], acc[i][j]);
        if (t + 1 < nt) {
            asm volatile("s_waitcnt vmcnt(0)" ::: "memory");
            __syncthreads();
            cur ^= 1;
        }
    }
}

// ---------- combine GEMMs (both modalities, one launch), fp8 out ----------
__global__ void __launch_bounds__(256)
gemm_combine2(const unsigned char* __restrict__ Pv, const unsigned char* __restrict__ WvT,
              unsigned char* __restrict__ Cv,
              const unsigned char* __restrict__ Pa, const unsigned char* __restrict__ WaT,
              unsigned char* __restrict__ Ca)
{
    __shared__ __align__(16) unsigned char As[2 * 16384];
    __shared__ __align__(16) unsigned char Bs[2 * 16384];
    int id = blockIdx.x;
    const unsigned char *A, *BT; unsigned char* C; int D, N, bm, bn;
    if (id < 16) { A = Pv; BT = WvT; C = Cv; D = CDV; N = CDA; bm = (id & 3) * 128; bn = (id >> 2) * 128; }
    else { id -= 16; A = Pa; BT = WaT; C = Ca; D = CDA; N = CDV; bm = (id & 3) * 128; bn = (id >> 2) * 128; }

    f4v acc[4][4] = {};
    int tid = threadIdx.x;
    gemm_phase_fp8(A, BT, D, bm, bn, tid, As, Bs, acc);

    const int lane = tid & 63;
    const int w    = tid >> 6;
    const int wr   = (w >> 1) * 64, wc = (w & 1) * 64;
    const int row0 = (lane >> 4) * 4, col = lane & 15;
#pragma unroll
    for (int i = 0; i < 4; ++i)
#pragma unroll
        for (int j = 0; j < 4; ++j)
#pragma unroll
            for (int e = 0; e < 4; ++e) {
                int m = bm + wr + i * 16 + row0 + e;
                int n = bn + wc + j * 16 + col;
                C[(size_t)m * N + n] = f2f8(acc[i][j][e]);
            }
}

// ---------- fused dual-GEMM + softplus-energy reduce (one kernel per modality) ----------
// A (features) streamed global->register, single areg[4] bank; next-step A-loads
// interleaved after each areg[i]'s last MFMA use (WAR-safe) so they overlap the
// cluster. B staged via global_load_lds into 2x16KB LDS ring (both-sides XOR
// swizzle). Z template makes NT1/D1/D2 constexpr -> pointer switch and t*128
// offsets fold. Register budget: 128 AGPR acc + ~110 VGPR <= 256 (no spill).
template<int Z>
__global__ void __launch_bounds__(256, 2)
fused_energy(const unsigned char* __restrict__ A1, const unsigned char* __restrict__ B1,
             const unsigned char* __restrict__ A2, const unsigned char* __restrict__ B2,
             float* __restrict__ out)
{
    constexpr int D1  = (Z == 0) ? CDV : CDA;
    constexpr int D2  = (Z == 0) ? CDA : CDV;
    constexpr int NT1 = D1 / 128;
    constexpr int NT  = (D1 + D2) / 128;

    __shared__ __align__(16) unsigned char Bs[2][16384];

    const int tid  = threadIdx.x;
    const int lane = tid & 63;
    const int w    = tid >> 6;
    const int wr   = (w >> 1) * 64;
    const int wc   = (w & 1) * 64;
    const int lr   = lane & 15;
    const int hi   = lane >> 4;
    const int bm   = blockIdx.x * 128, bn = blockIdx.y * 128;

    // B staging bases (pre-swizzled source chunk), wave-uniform LDS dest
    const unsigned char* gB1[4];
    const unsigned char* gB2[4];
    int wbase[4];
#pragma unroll
    for (int it = 0; it < 4; ++it) {
        int idx   = it * 256 + tid;
        int row   = idx >> 3;
        int sch   = (idx & 7) ^ (row & 7);
        wbase[it] = (idx & ~63) * 16;
        gB1[it]   = B1 + (size_t)(bn + row) * D1 + sch * 16;
        gB2[it]   = B2 + (size_t)(bn + row) * D2 + sch * 16;
    }
    // A fragment base pointers (per-lane direct global)
    const unsigned char* pA1[4];
    const unsigned char* pA2[4];
#pragma unroll
    for (int f = 0; f < 4; ++f) {
        size_t row = (size_t)(bm + wr + f * 16 + lr);
        pA1[f] = A1 + row * D1 + hi * 32;
        pA2[f] = A2 + row * D2 + hi * 32;
    }

    auto stageB = [&](int buf, int t) {
#pragma unroll
        for (int it = 0; it < 4; ++it) {
            const unsigned char* src = (t < NT1) ? gB1[it] + t * 128
                                                 : gB2[it] + (t - NT1) * 128;
            __builtin_amdgcn_global_load_lds(
                (const __attribute__((address_space(1))) unsigned int*)src,
                (__attribute__((address_space(3))) unsigned int*)(&Bs[buf][0] + wbase[it]),
                16, 0, 0);
        }
    };

    v8i areg[4];
    auto loadAf = [&](int f, int t) {     // f, t always unroll-constant
        const unsigned char* p = (t < NT1) ? pA1[f] + t * 128
                                           : pA2[f] + (t - NT1) * 128;
        i4v lo = *(const i4v*)p;
        i4v h  = *(const i4v*)(p + 16);
        v8i r;
        r[0] = lo[0]; r[1] = lo[1]; r[2] = lo[2]; r[3] = lo[3];
        r[4] = h[0];  r[5] = h[1];  r[6] = h[2];  r[7] = h[3];
        areg[f] = r;
    };

    f4v acc1[4][4] = {};
    f4v acc2[4][4] = {};

    // prologue
    stageB(0, 0);
#pragma unroll
    for (int f = 0; f < 4; ++f) loadAf(f, 0);
    asm volatile("s_waitcnt vmcnt(0)" ::: "memory");
    __builtin_amdgcn_s_barrier();

#pragma unroll
    for (int t = 0; t < NT; ++t) {
        const int buf = t & 1;
        v8i bfr[4];
#pragma unroll
        for (int j = 0; j < 4; ++j)
            bfr[j] = ld_frag(&Bs[buf][0], wc + j * 16 + lr, hi);
        if (t + 1 < NT) stageB(buf ^ 1, t + 1);
        __builtin_amdgcn_s_setprio(1);
#pragma unroll
        for (int i = 0; i < 4; ++i) {
            if (t < NT1) {
#pragma unroll
                for (int j = 0; j < 4; ++j)
                    acc1[i][j] = MFMA_FP8(areg[i], bfr[j], acc1[i][j]);
            } else {
#pragma unroll
                for (int j = 0; j < 4; ++j)
                    acc2[i][j] = MFMA_FP8(areg[i], bfr[j], acc2[i][j]);
            }
            if (t + 1 < NT) loadAf(i, t + 1);   // reload areg[i] after its last use
        }
        __builtin_amdgcn_s_setprio(0);
        if (t + 1 < NT) {
            asm volatile("s_waitcnt vmcnt(0)" ::: "memory");
            __builtin_amdgcn_s_barrier();
        }
    }

    float local = 0.f;
#pragma unroll
    for (int i = 0; i < 4; ++i)
#pragma unroll
        for (int j = 0; j < 4; ++j)
#pragma unroll
            for (int e = 0; e < 4; ++e) {
                float iv = acc1[i][j][e];
                float cv = acc2[i][j][e];
                float sal = 0.3f * cv * cv + 0.7f * iv * iv;
                float t   = sal * iv;
                local += fmaxf(t, 0.f) + __logf(1.f + __expf(-fabsf(t)));
            }
#pragma unroll
    for (int o = 32; o > 0; o >>= 1) local += __shfl_down(local, o);
    __shared__ float wred[4];
    if (lane == 0) wred[w] = local;
    __syncthreads();
    if (tid == 0) atomicAdd(out, -(wred[0] + wred[1] + wred[2] + wred[3]));
}

// ---------- launch ----------
extern "C" void kernel_launch(void* const* d_in, const int* in_sizes, int n_in,
                              void* d_out, int out_size, void* d_ws, size_t ws_size,
                              hipStream_t stream)
{
    const float* fv = (const float*)d_in[0];   // (8,2048,768)
    const float* fa = (const float*)d_in[1];   // (8,2048,512)
    const float* pv = (const float*)d_in[2];   // (512,768)
    const float* pa = (const float*)d_in[3];   // (512,512)
    const float* wv = (const float*)d_in[4];   // (768,512) proj_audio_to_vision
    const float* wa = (const float*)d_in[5];   // (512,768) proj_vision_to_audio
    float* out = (float*)d_out;

    size_t off = 0;
    auto carve = [&](size_t bytes) {
        unsigned char* p = (unsigned char*)d_ws + off;
        off += ((bytes + 255) & ~(size_t)255);
        return p;
    };
    unsigned char* Gv  = carve((size_t)CM * CDV);
    unsigned char* Sv  = carve((size_t)CM * CDV);
    unsigned char* Ga  = carve((size_t)CM * CDA);
    unsigned char* Sa  = carve((size_t)CM * CDA);
    unsigned char* Pv  = carve((size_t)CK * CDV);
    unsigned char* Pa  = carve((size_t)CK * CDA);
    unsigned char* WvT = carve((size_t)CDA * CDV);
    unsigned char* WaT = carve((size_t)CDV * CDA);
    unsigned char* Cv  = carve((size_t)CK * CDA);
    unsigned char* Ca  = carve((size_t)CK * CDV);

    (void)hipMemsetAsync(d_out, 0, sizeof(float), stream);

    constexpr int NS = CM * (CDV / 8) + CM * (CDA / 8);
    prep_smooth_all<<<(NS + 255) / 256, 256, 0, stream>>>(fv, fa, Gv, Sv, Ga, Sa);

    constexpr int NP = CK * CDV / 8 + CK * CDA / 8 + 2 * CDV * CDA;
    prep_small<<<(NP + 255) / 256, 256, 0, stream>>>(pv, pa, wv, wa, Pv, Pa, WvT, WaT);

    gemm_combine2<<<16 + 24, 256, 0, stream>>>(Pv, WvT, Cv, Pa, WaT, Ca);

    // e_v: intra = Gv @ Pv^T (D=768); cross = Sa @ Cv^T (D=512)
    fused_energy<0><<<dim3(CM / 128, CK / 128), 256, 0, stream>>>(Gv, Pv, Sa, Cv, out);
    // e_a: intra = Ga @ Pa^T (D=512); cross = Sv @ Ca^T (D=768)
    fused_energy<1><<<dim3(CM / 128, CK / 128), 256, 0, stream>>>(Ga, Pa, Sv, Ca, out);
}